// Round 8
// baseline (464.502 us; speedup 1.0000x reference)
//
#include <hip/hip_runtime.h>

// 2-layer GCN, R20: wide gathers + packed u64 LDS atomics.
// R19 post-mortem: agg1 136us, VALU ~53us (~10 wave-inst/edge), LDS-atomic
// pipe ~40us, HBM ~35us -- instruction-issue dominated. R20 halves per-edge
// instructions twice over:
// (a) uint4 gathers: 16 lanes x 16B cover one 256B h1 row -> 1 load + 1
//     bpermute per 4 edges (agg1); 8 lanes/row -> 8 edges/load (agg2).
// (b) h stored as BIASED u16 fixed-point (q13 + 32768, always positive -> no
//     cross-field borrow), so one ds_add_u64 accumulates the (f, f+64) pair:
//     1 atomic/edge instead of 2. Field overflow needs deg>65534: impossible.
//     Finalize subtracts (cnt+1)*32768 per field (cnt now passed to agg).
// Staging/scans/GEMM cores unchanged from R19.

#define N_NODES 100000
#define NBLK2 256          // staging partition blocks
#define NBUCK2 782         // ceil(100000/128) dst buckets of 128
#define NCH 13             // src chunks of 8192 (s>>13)
#define NKEY (NBUCK2 * NCH) // 10166

#define QS   8192.0f           // 2^13 fixed-point scale
#define IQS  1.220703125e-4f   // 2^-13

typedef __attribute__((ext_vector_type(8))) short short8;
typedef __attribute__((ext_vector_type(4))) float f32x4;

// ---------- bf16 helpers (RN-even) ----------
__device__ __forceinline__ unsigned short f2bf(float f) {
    union { float f; unsigned u; } c; c.f = f;
    unsigned r = (c.u + 0x7fffu + ((c.u >> 16) & 1u)) >> 16;
    return (unsigned short)r;
}
__device__ __forceinline__ unsigned packbf(float a, float b) {
    return (unsigned)f2bf(a) | ((unsigned)f2bf(b) << 16);
}
// f32 -> saturated s16 fixed point (x 2^13), BIASED by +32768 (u16, >=1)
__device__ __forceinline__ unsigned short q13b(float v) {
    int i = __float2int_rn(v * QS);
    i = i < -32767 ? -32767 : (i > 32767 ? 32767 : i);
    return (unsigned short)(i + 32768);
}
// split one gathered u32 (two biased u16 fields) into a u64 addend
__device__ __forceinline__ unsigned long long pk64(unsigned w) {
    return ((unsigned long long)(w >> 16) << 32) | (unsigned long long)(w & 0xffffu);
}

// ---------- edge dtype detection (one wave) ----------
__global__ void detect64_k(const unsigned long long* __restrict__ ei, int* __restrict__ flag) {
    unsigned long long v = ei[threadIdx.x & 63];
    unsigned long long bad = __ballot(v >= (1ULL << 32));
    if (threadIdx.x == 0) *flag = (bad == 0ULL) ? 1 : 0;
}

__device__ __forceinline__ int edge_at(const void* ei, int is64, long long idx) {
    if (is64) return (int)((const long long*)ei)[idx];
    return ((const int*)ei)[idx];
}

// ---------- pass 1: per-block [bucket x chunk] LDS histogram, block-major out ----------
__global__ __launch_bounds__(256) void count1_k(const void* __restrict__ ei,
                                                const int* __restrict__ flag,
                                                int* __restrict__ bhist, int E) {
    __shared__ int lh[NKEY];
    int t = threadIdx.x;
    for (int i = t; i < NKEY; i += 256) lh[i] = 0;
    __syncthreads();
    int is64 = *flag;
    int C = (E + NBLK2 - 1) / NBLK2;
    int lo = blockIdx.x * C;
    int hi = lo + C; if (hi > E) hi = E;
    for (int e = lo + t; e < hi; e += 256) {
        int s = edge_at(ei, is64, e);
        int d = edge_at(ei, is64, (long long)E + e);
        if ((unsigned)d >= (unsigned)N_NODES) continue;
        if ((unsigned)s >= (unsigned)N_NODES) s = 0;
        atomicAdd(&lh[(d >> 7) * NCH + (s >> 13)], 1);
    }
    __syncthreads();
    int* dst = bhist + (size_t)blockIdx.x * NKEY;   // block-major: coalesced
    for (int i = t; i < NKEY; i += 256) dst[i] = lh[i];
}

// ---------- column sums over partitions (coalesced across keys) ----------
__global__ void colsum_k(const int* __restrict__ bhist, int* __restrict__ colsum) {
    int k = blockIdx.x * 256 + threadIdx.x;
    if (k >= NKEY) return;
    int s = 0;
#pragma unroll 4
    for (int b = 0; b < NBLK2; ++b) s += bhist[(size_t)b * NKEY + k];
    colsum[k] = s;
}

// ---------- generic exclusive scan, 1024 elems/block ----------
__global__ void scan1_k(const int* __restrict__ cnt, int* __restrict__ partial,
                        int* __restrict__ bsum, int n) {
    __shared__ int sm[256];
    int t = threadIdx.x;
    int base = blockIdx.x * 1024 + t * 4;
    int v[4]; int loc = 0;
#pragma unroll
    for (int j = 0; j < 4; ++j) { v[j] = (base + j < n) ? cnt[base + j] : 0; loc += v[j]; }
    sm[t] = loc; __syncthreads();
    for (int off = 1; off < 256; off <<= 1) {
        int x = (t >= off) ? sm[t - off] : 0;
        __syncthreads();
        sm[t] += x;
        __syncthreads();
    }
    int incl = sm[t];
    int run = incl - loc;
    if (t == 255) bsum[blockIdx.x] = incl;
#pragma unroll
    for (int j = 0; j < 4; ++j) {
        if (base + j < n) partial[base + j] = run;
        run += v[j];
    }
}

// exclusive scan of block sums in place (16 per thread, up to 4096)
__global__ void scan2_k(int* __restrict__ bsum, int nb) {
    __shared__ int sm[256];
    int t = threadIdx.x;
    int v[16]; int loc = 0;
#pragma unroll
    for (int i = 0; i < 16; ++i) {
        int idx = t * 16 + i;
        v[i] = (idx < nb) ? bsum[idx] : 0;
        loc += v[i];
    }
    sm[t] = loc; __syncthreads();
    for (int off = 1; off < 256; off <<= 1) {
        int x = (t >= off) ? sm[t - off] : 0;
        __syncthreads();
        sm[t] += x;
        __syncthreads();
    }
    int run = sm[t] - loc;
#pragma unroll
    for (int i = 0; i < 16; ++i) {
        int idx = t * 16 + i;
        if (idx < nb) bsum[idx] = run;
        run += v[i];
    }
}

// finalize key-base scan in place; also emit total valid count
__global__ void scanadd_k(const int* __restrict__ bsum, int* __restrict__ arr,
                          const int* __restrict__ raw, int* __restrict__ tot, int n) {
    int base = blockIdx.x * 1024 + threadIdx.x * 4;
    int add = bsum[blockIdx.x];
#pragma unroll
    for (int j = 0; j < 4; ++j) {
        int i = base + j;
        if (i < n) {
            int v = arr[i] + add;
            arr[i] = v;
            if (i == n - 1) *tot = v + raw[i];
        }
    }
}

// per-(blk,key) base = keybase[key] + prefix over partitions (coalesced)
__global__ void colprefix_k(const int* __restrict__ bhist, const int* __restrict__ keybase,
                            int* __restrict__ bbase) {
    int k = blockIdx.x * 256 + threadIdx.x;
    if (k >= NKEY) return;
    int run = keybase[k];
#pragma unroll 8
    for (int b = 0; b < NBLK2; ++b) {
        size_t i = (size_t)b * NKEY + k;
        int c = bhist[i];
        bbase[i] = run;
        run += c;
    }
}

// dinv straight from degree
__global__ void dinv_k(const int* __restrict__ cnt, float* __restrict__ dinv, int n) {
    int i = blockIdx.x * 256 + threadIdx.x;
    if (i < n) dinv[i] = rsqrtf((float)(cnt[i] + 1));  // +1 self-loop
}

// ---------- pass 2: staging write sorted by (bucket, chunk) ----------
__global__ __launch_bounds__(256) void write1_k(const void* __restrict__ ei,
                                                const int* __restrict__ flag,
                                                const int* __restrict__ bbase,
                                                unsigned* __restrict__ pairs, int E) {
    __shared__ int lofs[NKEY];
    int t = threadIdx.x;
    const int* src0 = bbase + (size_t)blockIdx.x * NKEY;
    for (int i = t; i < NKEY; i += 256) lofs[i] = src0[i];
    __syncthreads();
    int is64 = *flag;
    int C = (E + NBLK2 - 1) / NBLK2;
    int lo = blockIdx.x * C;
    int hi = lo + C; if (hi > E) hi = E;
    for (int e = lo + t; e < hi; e += 256) {
        int s = edge_at(ei, is64, e);
        int d = edge_at(ei, is64, (long long)E + e);
        if ((unsigned)d >= (unsigned)N_NODES) continue;
        if ((unsigned)s >= (unsigned)N_NODES) s = 0;
        int key = (d >> 7) * NCH + (s >> 13);
        int p = atomicAdd(&lofs[key], 1);
        pairs[p] = (unsigned)s | ((unsigned)(d & 127) << 17);
    }
}

// ---------- degrees from staged pairs: one block per bucket ----------
__global__ __launch_bounds__(256) void degree_k(const unsigned* __restrict__ pairs,
                                                const int* __restrict__ keybase,
                                                const int* __restrict__ tot,
                                                int* __restrict__ cnt, int Nn) {
    __shared__ int lh[128];
    int b = blockIdx.x;
    int t = threadIdx.x;
    if (t < 128) lh[t] = 0;
    __syncthreads();
    int lo = keybase[b * NCH];
    int hi = (b == NBUCK2 - 1) ? *tot : keybase[(b + 1) * NCH];
    for (int i = lo + t; i < hi; i += 256) {
        unsigned p = __builtin_nontemporal_load(pairs + i);
        atomicAdd(&lh[p >> 17], 1);
    }
    __syncthreads();
    int n0 = b << 7;
    if (t < 128 && n0 + t < Nn) cnt[n0 + t] = lh[t];
}

// ---------- weight prep: W^T in bf16 ----------
__global__ void prep_w_k(const float* __restrict__ W1, const float* __restrict__ W2,
                         unsigned short* __restrict__ w1bf, unsigned short* __restrict__ w2bf) {
    int i = blockIdx.x * 256 + threadIdx.x;
    if (i < 128 * 128) { int k = i >> 7, f = i & 127; w1bf[f * 128 + k] = f2bf(W1[i]); }
    if (i < 128 * 64)  { int k = i >> 6, f = i & 63;  w2bf[f * 128 + k] = f2bf(W2[i]); }
}

// ---------- GEMM1 (MFMA): h1[n] = dinv[n]*(x @ W1), biased-u16 interleaved ----------
// h1[n][q] u32 = u16b(feat q) | u16b(feat q+64) << 16, q < 64; scale 2^13
__global__ __launch_bounds__(256) void gemm1_k(const float* __restrict__ x,
                                               const unsigned short* __restrict__ w1bf,
                                               const float* __restrict__ dinv,
                                               unsigned* __restrict__ h1, int Nn) {
    __shared__ __align__(16) unsigned short sA[128][136];  // W1^T [feat][k]
    __shared__ __align__(16) unsigned short sB[64][136];   // x [node][k] bf16
    int tid = threadIdx.x;
    int n0g = blockIdx.x * 64;
    {
        const uint4* src = (const uint4*)w1bf;
#pragma unroll
        for (int l = 0; l < 8; ++l) {
            int idx = tid + l * 256;
            int f = idx >> 4, kq = idx & 15;
            *(uint4*)&sA[f][kq * 8] = src[idx];
        }
    }
    {
        int n = tid >> 2, kq = tid & 3;
        int gn = n0g + n; if (gn >= Nn) gn = Nn - 1;
        const float4* xr = (const float4*)(x + (size_t)gn * 128 + kq * 32);
        unsigned short* dst = &sB[n][kq * 32];
#pragma unroll
        for (int i = 0; i < 8; ++i) {
            float4 v = xr[i];
            dst[i * 4 + 0] = f2bf(v.x); dst[i * 4 + 1] = f2bf(v.y);
            dst[i * 4 + 2] = f2bf(v.z); dst[i * 4 + 3] = f2bf(v.w);
        }
    }
    __syncthreads();
    int wave = tid >> 6, lane = tid & 63;
    int quad = lane >> 4, l16 = lane & 15;
    f32x4 z = {0.f, 0.f, 0.f, 0.f};
    f32x4 acc[8];
#pragma unroll
    for (int t = 0; t < 8; ++t) acc[t] = z;
#pragma unroll
    for (int kk = 0; kk < 4; ++kk) {
        int kb = kk * 32 + quad * 8;
        short8 a = *(const short8*)&sB[wave * 16 + l16][kb];
#pragma unroll
        for (int ft = 0; ft < 8; ++ft) {
            short8 b = *(const short8*)&sA[ft * 16 + l16][kb];
            acc[ft] = __builtin_amdgcn_mfma_f32_16x16x32_bf16(a, b, acc[ft], 0, 0, 0);
        }
    }
    float dv[4];
#pragma unroll
    for (int r = 0; r < 4; ++r) {
        int gn = n0g + wave * 16 + quad * 4 + r;
        if (gn >= Nn) gn = Nn - 1;
        dv[r] = dinv[gn];
    }
    __syncthreads();  // reuse sA as transpose buffer (biased u16 now)
    unsigned short (*sC)[136] = sA;
#pragma unroll
    for (int ft = 0; ft < 8; ++ft)
#pragma unroll
        for (int r = 0; r < 4; ++r)
            sC[wave * 16 + quad * 4 + r][ft * 16 + l16] = q13b(dv[r] * acc[ft][r]);
    __syncthreads();
#pragma unroll
    for (int l = 0; l < 4; ++l) {
        int idx = tid + l * 256;
        int row = idx >> 4, g = idx & 15;
        int gn = n0g + row;
        if (gn < Nn) {
            ushort4 A = *(ushort4*)&sC[row][g * 4];
            ushort4 B = *(ushort4*)&sC[row][g * 4 + 64];
            uint4 o;
            o.x = (unsigned)A.x | ((unsigned)B.x << 16);
            o.y = (unsigned)A.y | ((unsigned)B.y << 16);
            o.z = (unsigned)A.z | ((unsigned)B.z << 16);
            o.w = (unsigned)A.w | ((unsigned)B.w << 16);
            *(uint4*)&h1[(size_t)gn * 64 + g * 4] = o;
        }
    }
}

// ---------- GEMM2 (MFMA): h2[n] = dinv[n]*(hr @ W2), biased-u16 interleaved ----------
// h2[n][q] u32 = u16b(feat q) | u16b(feat q+32) << 16, q < 32; scale 2^13
__global__ __launch_bounds__(256) void gemm2_k(const unsigned* __restrict__ hr,
                                               const unsigned short* __restrict__ w2bf,
                                               const float* __restrict__ dinv,
                                               unsigned* __restrict__ h2, int Nn) {
    __shared__ __align__(16) unsigned short sA[64][136];
    __shared__ __align__(16) unsigned short sB[64][136];
    int tid = threadIdx.x;
    int n0g = blockIdx.x * 64;
    {
        const uint4* src = (const uint4*)w2bf;
#pragma unroll
        for (int l = 0; l < 4; ++l) {
            int idx = tid + l * 256;
            int f = idx >> 4, kq = idx & 15;
            *(uint4*)&sA[f][kq * 8] = src[idx];
        }
    }
    {
        const uint4* src = (const uint4*)hr;
#pragma unroll
        for (int l = 0; l < 4; ++l) {
            int idx = tid + l * 256;
            int row = idx >> 4, q = idx & 15;
            int gn = n0g + row; if (gn >= Nn) gn = Nn - 1;
            *(uint4*)&sB[row][q * 8] = src[(size_t)gn * 16 + q];
        }
    }
    __syncthreads();
    int wave = tid >> 6, lane = tid & 63;
    int quad = lane >> 4, l16 = lane & 15;
    f32x4 z = {0.f, 0.f, 0.f, 0.f};
    f32x4 acc[4];
#pragma unroll
    for (int t = 0; t < 4; ++t) acc[t] = z;
#pragma unroll
    for (int kk = 0; kk < 4; ++kk) {
        int kb = kk * 32 + quad * 8;
        short8 a = *(const short8*)&sB[wave * 16 + l16][kb];
#pragma unroll
        for (int ft = 0; ft < 4; ++ft) {
            short8 b = *(const short8*)&sA[ft * 16 + l16][kb];
            acc[ft] = __builtin_amdgcn_mfma_f32_16x16x32_bf16(a, b, acc[ft], 0, 0, 0);
        }
    }
    float dv[4];
#pragma unroll
    for (int r = 0; r < 4; ++r) {
        int gn = n0g + wave * 16 + quad * 4 + r;
        if (gn >= Nn) gn = Nn - 1;
        dv[r] = dinv[gn];
    }
    __syncthreads();
    unsigned short (*sC)[136] = sA;
#pragma unroll
    for (int ft = 0; ft < 4; ++ft)
#pragma unroll
        for (int r = 0; r < 4; ++r)
            sC[wave * 16 + quad * 4 + r][ft * 16 + l16] = q13b(dv[r] * acc[ft][r]);
    __syncthreads();
#pragma unroll
    for (int l = 0; l < 2; ++l) {
        int idx = tid + l * 256;
        int row = idx >> 3, g = idx & 7;
        int gn = n0g + row;
        if (gn < Nn) {
            ushort4 A = *(ushort4*)&sC[row][g * 4];
            ushort4 B = *(ushort4*)&sC[row][g * 4 + 32];
            uint4 o;
            o.x = (unsigned)A.x | ((unsigned)B.x << 16);
            o.y = (unsigned)A.y | ((unsigned)B.y << 16);
            o.z = (unsigned)A.z | ((unsigned)B.z << 16);
            o.w = (unsigned)A.w | ((unsigned)B.w << 16);
            *(uint4*)&h2[(size_t)gn * 32 + g * 4] = o;
        }
    }
}

// ---------- agg1: bucket(128 dst), u64 LDS accum, uint4 gathers (4 edges/load) ----------
__global__ __launch_bounds__(1024) void agg1_k(const unsigned* __restrict__ h,
                                               const unsigned* __restrict__ pairs,
                                               const int* __restrict__ keybase,
                                               const int* __restrict__ tot,
                                               const int* __restrict__ cnt,
                                               const float* __restrict__ dinv,
                                               const float* __restrict__ bias,
                                               unsigned* __restrict__ out, int Nn) {
    extern __shared__ unsigned long long acc2[];   // [128][64] u64 (lo=f, hi=f+64)
    int tid = threadIdx.x, lane = tid & 63, wave = tid >> 6;
    int qtr = lane >> 4, fq = lane & 15;   // 16 lanes x 16B = one 256B row
    int b = blockIdx.x, n0 = b << 7;
    const uint4* hq = (const uint4*)h;     // row = 16 uint4
    // init with self rows (biased fields count as 1 add; nadds = cnt+1)
    for (int i = tid; i < 128 * 64; i += 1024) {
        int row = i >> 6, q = i & 63;
        unsigned u = (n0 + row < Nn) ? h[(size_t)(n0 + row) * 64 + q] : 0u;
        acc2[row * 64 + q] = pk64(u);
    }
    __syncthreads();
    int lo = keybase[b * NCH];
    int hi = (b == NBUCK2 - 1) ? *tot : keybase[(b + 1) * NCH];
    for (int base = lo + wave * 64; base < hi; base += 1024) {
        int idx = base + lane;
        unsigned pv = pairs[(idx < hi) ? idx : (hi - 1)];
        int m = hi - base; if (m > 64) m = 64;
        int j = 0;
        for (; j + 16 <= m; j += 16) {     // 4 passes x 4 edges
#pragma unroll
            for (int k = 0; k < 4; ++k) {
                unsigned p = __shfl(pv, j + 4 * k + qtr);
                uint4 u = hq[((p & 0x1FFFFu) << 4) + fq];
                unsigned long long* a = &acc2[((p >> 17) << 6) + 4 * fq];
                atomicAdd(a + 0, pk64(u.x));
                atomicAdd(a + 1, pk64(u.y));
                atomicAdd(a + 2, pk64(u.z));
                atomicAdd(a + 3, pk64(u.w));
            }
        }
        for (; j + 4 <= m; j += 4) {
            unsigned p = __shfl(pv, j + qtr);
            uint4 u = hq[((p & 0x1FFFFu) << 4) + fq];
            unsigned long long* a = &acc2[((p >> 17) << 6) + 4 * fq];
            atomicAdd(a + 0, pk64(u.x));
            atomicAdd(a + 1, pk64(u.y));
            atomicAdd(a + 2, pk64(u.z));
            atomicAdd(a + 3, pk64(u.w));
        }
        if (j < m) {                        // 1..3 edges left
            int q = j + qtr;
            unsigned p = __shfl(pv, (q < m) ? q : j);
            if (q < m) {
                uint4 u = hq[((p & 0x1FFFFu) << 4) + fq];
                unsigned long long* a = &acc2[((p >> 17) << 6) + 4 * fq];
                atomicAdd(a + 0, pk64(u.x));
                atomicAdd(a + 1, pk64(u.y));
                atomicAdd(a + 2, pk64(u.z));
                atomicAdd(a + 3, pk64(u.w));
            }
        }
    }
    __syncthreads();
    int nn = Nn - n0; if (nn > 128) nn = 128;
    // out word q of hr = packbf(feat 2q, feat 2q+1); feat f<64 = lo(acc2[f]),
    // f>=64 = hi(acc2[f-64]); debias by nadds*32768 per field
    for (int i = tid; i < nn * 64; i += 1024) {
        int row = i >> 6, q = i & 63;
        float di = dinv[n0 + row];
        int nadds = cnt[n0 + row] + 1;
        float deb = (float)nadds * 32768.0f;
        int f0 = 2 * q, f1 = 2 * q + 1;
        unsigned long long v0 = acc2[row * 64 + (f0 & 63)];
        unsigned long long v1 = acc2[row * 64 + (f1 & 63)];
        float s0 = ((float)(unsigned)((f0 < 64) ? (v0 & 0xffffffffu) : (v0 >> 32)) - deb) * IQS;
        float s1 = ((float)(unsigned)((f1 < 64) ? (v1 & 0xffffffffu) : (v1 >> 32)) - deb) * IQS;
        float r0 = fmaxf(fmaf(di, s0, bias[f0]), 0.f);
        float r1 = fmaxf(fmaf(di, s1, bias[f1]), 0.f);
        out[(size_t)(n0 + row) * 64 + q] = packbf(r0, r1);
    }
}

// ---------- agg2: bucket(128 dst), u64 LDS accum, uint4 gathers (8 edges/load) ----------
__global__ __launch_bounds__(1024) void agg2_k(const unsigned* __restrict__ h,
                                               const unsigned* __restrict__ pairs,
                                               const int* __restrict__ keybase,
                                               const int* __restrict__ tot,
                                               const int* __restrict__ cnt,
                                               const float* __restrict__ dinv,
                                               const float* __restrict__ bias,
                                               float* __restrict__ out, int Nn) {
    __shared__ unsigned long long acc2[128 * 32];  // [128][32] u64 (lo=f, hi=f+32)
    int tid = threadIdx.x, lane = tid & 63, wave = tid >> 6;
    int oct = lane >> 3, fo = lane & 7;    // 8 lanes x 16B = one 128B row
    int b = blockIdx.x, n0 = b << 7;
    const uint4* hq = (const uint4*)h;     // row = 8 uint4
    for (int i = tid; i < 128 * 32; i += 1024) {
        int row = i >> 5, q = i & 31;
        unsigned u = (n0 + row < Nn) ? h[(size_t)(n0 + row) * 32 + q] : 0u;
        acc2[row * 32 + q] = pk64(u);
    }
    __syncthreads();
    int lo = keybase[b * NCH];
    int hi = (b == NBUCK2 - 1) ? *tot : keybase[(b + 1) * NCH];
    for (int base = lo + wave * 64; base < hi; base += 1024) {
        int idx = base + lane;
        unsigned pv = pairs[(idx < hi) ? idx : (hi - 1)];
        int m = hi - base; if (m > 64) m = 64;
        int j = 0;
        for (; j + 16 <= m; j += 16) {     // 2 passes x 8 edges
#pragma unroll
            for (int k = 0; k < 2; ++k) {
                unsigned p = __shfl(pv, j + 8 * k + oct);
                uint4 u = hq[((p & 0x1FFFFu) << 3) + fo];
                unsigned long long* a = &acc2[((p >> 17) << 5) + 4 * fo];
                atomicAdd(a + 0, pk64(u.x));
                atomicAdd(a + 1, pk64(u.y));
                atomicAdd(a + 2, pk64(u.z));
                atomicAdd(a + 3, pk64(u.w));
            }
        }
        for (; j + 8 <= m; j += 8) {
            unsigned p = __shfl(pv, j + oct);
            uint4 u = hq[((p & 0x1FFFFu) << 3) + fo];
            unsigned long long* a = &acc2[((p >> 17) << 5) + 4 * fo];
            atomicAdd(a + 0, pk64(u.x));
            atomicAdd(a + 1, pk64(u.y));
            atomicAdd(a + 2, pk64(u.z));
            atomicAdd(a + 3, pk64(u.w));
        }
        if (j < m) {                        // 1..7 edges left
            int q = j + oct;
            unsigned p = __shfl(pv, (q < m) ? q : j);
            if (q < m) {
                uint4 u = hq[((p & 0x1FFFFu) << 3) + fo];
                unsigned long long* a = &acc2[((p >> 17) << 5) + 4 * fo];
                atomicAdd(a + 0, pk64(u.x));
                atomicAdd(a + 1, pk64(u.y));
                atomicAdd(a + 2, pk64(u.z));
                atomicAdd(a + 3, pk64(u.w));
            }
        }
    }
    __syncthreads();
    int nn = Nn - n0; if (nn > 128) nn = 128;
    // out feat f<32 = lo(acc2[f]), f>=32 = hi(acc2[f-32]); debias
    for (int i = tid; i < nn * 64; i += 1024) {
        int row = i >> 6, f = i & 63;
        float di = dinv[n0 + row];
        int nadds = cnt[n0 + row] + 1;
        float deb = (float)nadds * 32768.0f;
        unsigned long long v = acc2[row * 32 + (f & 31)];
        float s = ((float)(unsigned)((f < 32) ? (v & 0xffffffffu) : (v >> 32)) - deb) * IQS;
        out[(size_t)(n0 + row) * 64 + f] = fmaf(di, s, bias[f]);
    }
}

// ---------- launch ----------
extern "C" void kernel_launch(void* const* d_in, const int* in_sizes, int n_in,
                              void* d_out, int out_size, void* d_ws, size_t ws_size,
                              hipStream_t stream) {
    const float* x  = (const float*)d_in[0];
    const void*  ei = d_in[1];
    const float* W1 = (const float*)d_in[2];
    const float* b1 = (const float*)d_in[3];
    const float* W2 = (const float*)d_in[4];
    const float* b2 = (const float*)d_in[5];

    const int N = N_NODES;
    const int E = in_sizes[1] / 2;

    char* w = (char*)d_ws;
    size_t off = 0;
    auto take = [&](size_t bytes) {
        void* p = w + off;
        off = (off + bytes + 255) & ~(size_t)255;
        return p;
    };
    int*   flag    = (int*)take(2 * sizeof(int));
    int*   tot     = flag + 1;
    int*   cnt     = (int*)take((size_t)N * 4);
    int*   bsumB   = (int*)take(4096 * 4);
    int*   colsum  = (int*)take((size_t)NKEY * 4);
    int*   keybase = (int*)take((size_t)NKEY * 4);
    float* dinv    = (float*)take((size_t)N * 4);
    unsigned* pairs = (unsigned*)take((size_t)E * 4);
    unsigned short* w1bf = (unsigned short*)take(128 * 128 * 2);
    unsigned short* w2bf = (unsigned short*)take(64 * 128 * 2);
    unsigned* hr   = (unsigned*)take((size_t)N * 64 * 4);   // bf16 [N][128] normal order
    unsigned* h2   = (unsigned*)take((size_t)N * 32 * 4);   // biased-u16 [N][64] interleaved
    (void)ws_size; (void)n_in; (void)out_size;

    // Staging tables ALIAS onto hr/h2 (both dead until after staging):
    //   bhist last read by colprefix_k; hr first written by agg1_k (later).
    //   bbase last read by write1_k;   h2 first written by gemm2_k (later).
    int* bhist = (int*)hr;
    int* bbase = (int*)h2;

    unsigned* h1 = (unsigned*)d_out;  // biased-u16 [N][128] interleaved, dead before agg2 writes

    const int nscanK = (NKEY + 1023) / 1024;   // 10
    const int ngridK = (NKEY + 255) / 256;     // 40

    detect64_k<<<1, 64, 0, stream>>>((const unsigned long long*)ei, flag);
    count1_k<<<NBLK2, 256, 0, stream>>>(ei, flag, bhist, E);
    colsum_k<<<ngridK, 256, 0, stream>>>(bhist, colsum);
    scan1_k<<<nscanK, 256, 0, stream>>>(colsum, keybase, bsumB, NKEY);
    scan2_k<<<1, 256, 0, stream>>>(bsumB, nscanK);
    scanadd_k<<<nscanK, 256, 0, stream>>>(bsumB, keybase, colsum, tot, NKEY);
    colprefix_k<<<ngridK, 256, 0, stream>>>(bhist, keybase, bbase);
    write1_k<<<NBLK2, 256, 0, stream>>>(ei, flag, bbase, pairs, E);
    degree_k<<<NBUCK2, 256, 0, stream>>>(pairs, keybase, tot, cnt, N);
    dinv_k<<<(N + 255) / 256, 256, 0, stream>>>(cnt, dinv, N);
    prep_w_k<<<64, 256, 0, stream>>>(W1, W2, w1bf, w2bf);

    gemm1_k<<<(N + 63) / 64, 256, 0, stream>>>(x, w1bf, dinv, h1, N);
    agg1_k<<<NBUCK2, 1024, 128 * 64 * 8, stream>>>(h1, pairs, keybase, tot, cnt, dinv, b1, hr, N);
    gemm2_k<<<(N + 63) / 64, 256, 0, stream>>>(hr, w2bf, dinv, h2, N);
    agg2_k<<<NBUCK2, 1024, 0, stream>>>(h2, pairs, keybase, tot, cnt, dinv, b2, (float*)d_out, N);
}

// Round 9
// 436.971 us; speedup vs baseline: 1.0630x; 1.0630x over previous
//
#include <hip/hip_runtime.h>

// 2-layer GCN, R21: R20's packed-u64 atomics with R19's bank-clean layout.
// R20 post-mortem: VALUBusy 39->18% (inst-count theory confirmed) but
// SQ_LDS_BANK_CONFLICT 400K->39.2M: acc2[row*64+4*fq] puts 16 lanes at 32B
// stride -> 4 bank-pairs -> 16-way conflict per ds_add_u64. R21:
// (a) one-u32-per-lane gathers again -> u64 atomic at acc2[row*64+lane],
//     stride-1 in u64 = minimum 4-cycle aliasing, no hot banks.
// (b) keep biased-u16 h + single ds_add_u64/edge (atomic issue halved vs R19;
//     numerics proven in R20 -- absmax unchanged).
// (c) NEW: pair is wave-uniform after __shfl -> readfirstlane routes row &
//     accumulator base math to SALU (free pipe); gather becomes SGPR-base +
//     hoisted lane offset. Per-edge VALU ~10 -> ~4.
// agg2: same u64 atomic at [row*32+fl] (bank = 2fl%32, row-independent = min
// 4-way). Staging/scans/GEMMs identical to R20 (proven).

#define N_NODES 100000
#define NBLK2 256          // staging partition blocks
#define NBUCK2 782         // ceil(100000/128) dst buckets of 128
#define NCH 13             // src chunks of 8192 (s>>13)
#define NKEY (NBUCK2 * NCH) // 10166

#define QS   8192.0f           // 2^13 fixed-point scale
#define IQS  1.220703125e-4f   // 2^-13

typedef __attribute__((ext_vector_type(8))) short short8;
typedef __attribute__((ext_vector_type(4))) float f32x4;

// ---------- bf16 helpers (RN-even) ----------
__device__ __forceinline__ unsigned short f2bf(float f) {
    union { float f; unsigned u; } c; c.f = f;
    unsigned r = (c.u + 0x7fffu + ((c.u >> 16) & 1u)) >> 16;
    return (unsigned short)r;
}
__device__ __forceinline__ unsigned packbf(float a, float b) {
    return (unsigned)f2bf(a) | ((unsigned)f2bf(b) << 16);
}
// f32 -> saturated s16 fixed point (x 2^13), BIASED by +32768 (u16)
__device__ __forceinline__ unsigned short q13b(float v) {
    int i = __float2int_rn(v * QS);
    i = i < -32767 ? -32767 : (i > 32767 ? 32767 : i);
    return (unsigned short)(i + 32768);
}
// split one gathered u32 (two biased u16 fields) into a u64 addend
__device__ __forceinline__ unsigned long long pk64(unsigned w) {
    return ((unsigned long long)(w >> 16) << 32) | (unsigned long long)(w & 0xffffu);
}
// wave-uniform scalar promotion
__device__ __forceinline__ unsigned sgpr(unsigned v) {
    return (unsigned)__builtin_amdgcn_readfirstlane((int)v);
}

// ---------- edge dtype detection (one wave) ----------
__global__ void detect64_k(const unsigned long long* __restrict__ ei, int* __restrict__ flag) {
    unsigned long long v = ei[threadIdx.x & 63];
    unsigned long long bad = __ballot(v >= (1ULL << 32));
    if (threadIdx.x == 0) *flag = (bad == 0ULL) ? 1 : 0;
}

__device__ __forceinline__ int edge_at(const void* ei, int is64, long long idx) {
    if (is64) return (int)((const long long*)ei)[idx];
    return ((const int*)ei)[idx];
}

// ---------- pass 1: per-block [bucket x chunk] LDS histogram, block-major out ----------
__global__ __launch_bounds__(256) void count1_k(const void* __restrict__ ei,
                                                const int* __restrict__ flag,
                                                int* __restrict__ bhist, int E) {
    __shared__ int lh[NKEY];
    int t = threadIdx.x;
    for (int i = t; i < NKEY; i += 256) lh[i] = 0;
    __syncthreads();
    int is64 = *flag;
    int C = (E + NBLK2 - 1) / NBLK2;
    int lo = blockIdx.x * C;
    int hi = lo + C; if (hi > E) hi = E;
    for (int e = lo + t; e < hi; e += 256) {
        int s = edge_at(ei, is64, e);
        int d = edge_at(ei, is64, (long long)E + e);
        if ((unsigned)d >= (unsigned)N_NODES) continue;
        if ((unsigned)s >= (unsigned)N_NODES) s = 0;
        atomicAdd(&lh[(d >> 7) * NCH + (s >> 13)], 1);
    }
    __syncthreads();
    int* dst = bhist + (size_t)blockIdx.x * NKEY;   // block-major: coalesced
    for (int i = t; i < NKEY; i += 256) dst[i] = lh[i];
}

// ---------- column sums over partitions (coalesced across keys) ----------
__global__ void colsum_k(const int* __restrict__ bhist, int* __restrict__ colsum) {
    int k = blockIdx.x * 256 + threadIdx.x;
    if (k >= NKEY) return;
    int s = 0;
#pragma unroll 4
    for (int b = 0; b < NBLK2; ++b) s += bhist[(size_t)b * NKEY + k];
    colsum[k] = s;
}

// ---------- generic exclusive scan, 1024 elems/block ----------
__global__ void scan1_k(const int* __restrict__ cnt, int* __restrict__ partial,
                        int* __restrict__ bsum, int n) {
    __shared__ int sm[256];
    int t = threadIdx.x;
    int base = blockIdx.x * 1024 + t * 4;
    int v[4]; int loc = 0;
#pragma unroll
    for (int j = 0; j < 4; ++j) { v[j] = (base + j < n) ? cnt[base + j] : 0; loc += v[j]; }
    sm[t] = loc; __syncthreads();
    for (int off = 1; off < 256; off <<= 1) {
        int x = (t >= off) ? sm[t - off] : 0;
        __syncthreads();
        sm[t] += x;
        __syncthreads();
    }
    int incl = sm[t];
    int run = incl - loc;
    if (t == 255) bsum[blockIdx.x] = incl;
#pragma unroll
    for (int j = 0; j < 4; ++j) {
        if (base + j < n) partial[base + j] = run;
        run += v[j];
    }
}

// exclusive scan of block sums in place (16 per thread, up to 4096)
__global__ void scan2_k(int* __restrict__ bsum, int nb) {
    __shared__ int sm[256];
    int t = threadIdx.x;
    int v[16]; int loc = 0;
#pragma unroll
    for (int i = 0; i < 16; ++i) {
        int idx = t * 16 + i;
        v[i] = (idx < nb) ? bsum[idx] : 0;
        loc += v[i];
    }
    sm[t] = loc; __syncthreads();
    for (int off = 1; off < 256; off <<= 1) {
        int x = (t >= off) ? sm[t - off] : 0;
        __syncthreads();
        sm[t] += x;
        __syncthreads();
    }
    int run = sm[t] - loc;
#pragma unroll
    for (int i = 0; i < 16; ++i) {
        int idx = t * 16 + i;
        if (idx < nb) bsum[idx] = run;
        run += v[i];
    }
}

// finalize key-base scan in place; also emit total valid count
__global__ void scanadd_k(const int* __restrict__ bsum, int* __restrict__ arr,
                          const int* __restrict__ raw, int* __restrict__ tot, int n) {
    int base = blockIdx.x * 1024 + threadIdx.x * 4;
    int add = bsum[blockIdx.x];
#pragma unroll
    for (int j = 0; j < 4; ++j) {
        int i = base + j;
        if (i < n) {
            int v = arr[i] + add;
            arr[i] = v;
            if (i == n - 1) *tot = v + raw[i];
        }
    }
}

// per-(blk,key) base = keybase[key] + prefix over partitions (coalesced)
__global__ void colprefix_k(const int* __restrict__ bhist, const int* __restrict__ keybase,
                            int* __restrict__ bbase) {
    int k = blockIdx.x * 256 + threadIdx.x;
    if (k >= NKEY) return;
    int run = keybase[k];
#pragma unroll 8
    for (int b = 0; b < NBLK2; ++b) {
        size_t i = (size_t)b * NKEY + k;
        int c = bhist[i];
        bbase[i] = run;
        run += c;
    }
}

// dinv straight from degree
__global__ void dinv_k(const int* __restrict__ cnt, float* __restrict__ dinv, int n) {
    int i = blockIdx.x * 256 + threadIdx.x;
    if (i < n) dinv[i] = rsqrtf((float)(cnt[i] + 1));  // +1 self-loop
}

// ---------- pass 2: staging write sorted by (bucket, chunk) ----------
__global__ __launch_bounds__(256) void write1_k(const void* __restrict__ ei,
                                                const int* __restrict__ flag,
                                                const int* __restrict__ bbase,
                                                unsigned* __restrict__ pairs, int E) {
    __shared__ int lofs[NKEY];
    int t = threadIdx.x;
    const int* src0 = bbase + (size_t)blockIdx.x * NKEY;
    for (int i = t; i < NKEY; i += 256) lofs[i] = src0[i];
    __syncthreads();
    int is64 = *flag;
    int C = (E + NBLK2 - 1) / NBLK2;
    int lo = blockIdx.x * C;
    int hi = lo + C; if (hi > E) hi = E;
    for (int e = lo + t; e < hi; e += 256) {
        int s = edge_at(ei, is64, e);
        int d = edge_at(ei, is64, (long long)E + e);
        if ((unsigned)d >= (unsigned)N_NODES) continue;
        if ((unsigned)s >= (unsigned)N_NODES) s = 0;
        int key = (d >> 7) * NCH + (s >> 13);
        int p = atomicAdd(&lofs[key], 1);
        pairs[p] = (unsigned)s | ((unsigned)(d & 127) << 17);
    }
}

// ---------- degrees from staged pairs: one block per bucket ----------
__global__ __launch_bounds__(256) void degree_k(const unsigned* __restrict__ pairs,
                                                const int* __restrict__ keybase,
                                                const int* __restrict__ tot,
                                                int* __restrict__ cnt, int Nn) {
    __shared__ int lh[128];
    int b = blockIdx.x;
    int t = threadIdx.x;
    if (t < 128) lh[t] = 0;
    __syncthreads();
    int lo = keybase[b * NCH];
    int hi = (b == NBUCK2 - 1) ? *tot : keybase[(b + 1) * NCH];
    for (int i = lo + t; i < hi; i += 256) {
        unsigned p = __builtin_nontemporal_load(pairs + i);
        atomicAdd(&lh[p >> 17], 1);
    }
    __syncthreads();
    int n0 = b << 7;
    if (t < 128 && n0 + t < Nn) cnt[n0 + t] = lh[t];
}

// ---------- weight prep: W^T in bf16 ----------
__global__ void prep_w_k(const float* __restrict__ W1, const float* __restrict__ W2,
                         unsigned short* __restrict__ w1bf, unsigned short* __restrict__ w2bf) {
    int i = blockIdx.x * 256 + threadIdx.x;
    if (i < 128 * 128) { int k = i >> 7, f = i & 127; w1bf[f * 128 + k] = f2bf(W1[i]); }
    if (i < 128 * 64)  { int k = i >> 6, f = i & 63;  w2bf[f * 128 + k] = f2bf(W2[i]); }
}

// ---------- GEMM1 (MFMA): h1[n] = dinv[n]*(x @ W1), biased-u16 interleaved ----------
// h1[n][q] u32 = u16b(feat q) | u16b(feat q+64) << 16, q < 64; scale 2^13
__global__ __launch_bounds__(256) void gemm1_k(const float* __restrict__ x,
                                               const unsigned short* __restrict__ w1bf,
                                               const float* __restrict__ dinv,
                                               unsigned* __restrict__ h1, int Nn) {
    __shared__ __align__(16) unsigned short sA[128][136];  // W1^T [feat][k]
    __shared__ __align__(16) unsigned short sB[64][136];   // x [node][k] bf16
    int tid = threadIdx.x;
    int n0g = blockIdx.x * 64;
    {
        const uint4* src = (const uint4*)w1bf;
#pragma unroll
        for (int l = 0; l < 8; ++l) {
            int idx = tid + l * 256;
            int f = idx >> 4, kq = idx & 15;
            *(uint4*)&sA[f][kq * 8] = src[idx];
        }
    }
    {
        int n = tid >> 2, kq = tid & 3;
        int gn = n0g + n; if (gn >= Nn) gn = Nn - 1;
        const float4* xr = (const float4*)(x + (size_t)gn * 128 + kq * 32);
        unsigned short* dst = &sB[n][kq * 32];
#pragma unroll
        for (int i = 0; i < 8; ++i) {
            float4 v = xr[i];
            dst[i * 4 + 0] = f2bf(v.x); dst[i * 4 + 1] = f2bf(v.y);
            dst[i * 4 + 2] = f2bf(v.z); dst[i * 4 + 3] = f2bf(v.w);
        }
    }
    __syncthreads();
    int wave = tid >> 6, lane = tid & 63;
    int quad = lane >> 4, l16 = lane & 15;
    f32x4 z = {0.f, 0.f, 0.f, 0.f};
    f32x4 acc[8];
#pragma unroll
    for (int t = 0; t < 8; ++t) acc[t] = z;
#pragma unroll
    for (int kk = 0; kk < 4; ++kk) {
        int kb = kk * 32 + quad * 8;
        short8 a = *(const short8*)&sB[wave * 16 + l16][kb];
#pragma unroll
        for (int ft = 0; ft < 8; ++ft) {
            short8 b = *(const short8*)&sA[ft * 16 + l16][kb];
            acc[ft] = __builtin_amdgcn_mfma_f32_16x16x32_bf16(a, b, acc[ft], 0, 0, 0);
        }
    }
    float dv[4];
#pragma unroll
    for (int r = 0; r < 4; ++r) {
        int gn = n0g + wave * 16 + quad * 4 + r;
        if (gn >= Nn) gn = Nn - 1;
        dv[r] = dinv[gn];
    }
    __syncthreads();  // reuse sA as transpose buffer (biased u16 now)
    unsigned short (*sC)[136] = sA;
#pragma unroll
    for (int ft = 0; ft < 8; ++ft)
#pragma unroll
        for (int r = 0; r < 4; ++r)
            sC[wave * 16 + quad * 4 + r][ft * 16 + l16] = q13b(dv[r] * acc[ft][r]);
    __syncthreads();
#pragma unroll
    for (int l = 0; l < 4; ++l) {
        int idx = tid + l * 256;
        int row = idx >> 4, g = idx & 15;
        int gn = n0g + row;
        if (gn < Nn) {
            ushort4 A = *(ushort4*)&sC[row][g * 4];
            ushort4 B = *(ushort4*)&sC[row][g * 4 + 64];
            uint4 o;
            o.x = (unsigned)A.x | ((unsigned)B.x << 16);
            o.y = (unsigned)A.y | ((unsigned)B.y << 16);
            o.z = (unsigned)A.z | ((unsigned)B.z << 16);
            o.w = (unsigned)A.w | ((unsigned)B.w << 16);
            *(uint4*)&h1[(size_t)gn * 64 + g * 4] = o;
        }
    }
}

// ---------- GEMM2 (MFMA): h2[n] = dinv[n]*(hr @ W2), biased-u16 interleaved ----------
// h2[n][q] u32 = u16b(feat q) | u16b(feat q+32) << 16, q < 32; scale 2^13
__global__ __launch_bounds__(256) void gemm2_k(const unsigned* __restrict__ hr,
                                               const unsigned short* __restrict__ w2bf,
                                               const float* __restrict__ dinv,
                                               unsigned* __restrict__ h2, int Nn) {
    __shared__ __align__(16) unsigned short sA[64][136];
    __shared__ __align__(16) unsigned short sB[64][136];
    int tid = threadIdx.x;
    int n0g = blockIdx.x * 64;
    {
        const uint4* src = (const uint4*)w2bf;
#pragma unroll
        for (int l = 0; l < 4; ++l) {
            int idx = tid + l * 256;
            int f = idx >> 4, kq = idx & 15;
            *(uint4*)&sA[f][kq * 8] = src[idx];
        }
    }
    {
        const uint4* src = (const uint4*)hr;
#pragma unroll
        for (int l = 0; l < 4; ++l) {
            int idx = tid + l * 256;
            int row = idx >> 4, q = idx & 15;
            int gn = n0g + row; if (gn >= Nn) gn = Nn - 1;
            *(uint4*)&sB[row][q * 8] = src[(size_t)gn * 16 + q];
        }
    }
    __syncthreads();
    int wave = tid >> 6, lane = tid & 63;
    int quad = lane >> 4, l16 = lane & 15;
    f32x4 z = {0.f, 0.f, 0.f, 0.f};
    f32x4 acc[4];
#pragma unroll
    for (int t = 0; t < 4; ++t) acc[t] = z;
#pragma unroll
    for (int kk = 0; kk < 4; ++kk) {
        int kb = kk * 32 + quad * 8;
        short8 a = *(const short8*)&sB[wave * 16 + l16][kb];
#pragma unroll
        for (int ft = 0; ft < 4; ++ft) {
            short8 b = *(const short8*)&sA[ft * 16 + l16][kb];
            acc[ft] = __builtin_amdgcn_mfma_f32_16x16x32_bf16(a, b, acc[ft], 0, 0, 0);
        }
    }
    float dv[4];
#pragma unroll
    for (int r = 0; r < 4; ++r) {
        int gn = n0g + wave * 16 + quad * 4 + r;
        if (gn >= Nn) gn = Nn - 1;
        dv[r] = dinv[gn];
    }
    __syncthreads();
    unsigned short (*sC)[136] = sA;
#pragma unroll
    for (int ft = 0; ft < 4; ++ft)
#pragma unroll
        for (int r = 0; r < 4; ++r)
            sC[wave * 16 + quad * 4 + r][ft * 16 + l16] = q13b(dv[r] * acc[ft][r]);
    __syncthreads();
#pragma unroll
    for (int l = 0; l < 2; ++l) {
        int idx = tid + l * 256;
        int row = idx >> 3, g = idx & 7;
        int gn = n0g + row;
        if (gn < Nn) {
            ushort4 A = *(ushort4*)&sC[row][g * 4];
            ushort4 B = *(ushort4*)&sC[row][g * 4 + 32];
            uint4 o;
            o.x = (unsigned)A.x | ((unsigned)B.x << 16);
            o.y = (unsigned)A.y | ((unsigned)B.y << 16);
            o.z = (unsigned)A.z | ((unsigned)B.z << 16);
            o.w = (unsigned)A.w | ((unsigned)B.w << 16);
            *(uint4*)&h2[(size_t)gn * 32 + g * 4] = o;
        }
    }
}

// ---------- agg1: bucket(128 dst), lane-owned u64 accum, scalar-routed edges ----------
__global__ __launch_bounds__(1024) void agg1_k(const unsigned* __restrict__ h,
                                               const unsigned* __restrict__ pairs,
                                               const int* __restrict__ keybase,
                                               const int* __restrict__ tot,
                                               const int* __restrict__ cnt,
                                               const float* __restrict__ dinv,
                                               const float* __restrict__ bias,
                                               unsigned* __restrict__ out, int Nn) {
    extern __shared__ unsigned long long acc2[];   // [128][64] u64, word w = feats (w, w+64)
    int tid = threadIdx.x, lane = tid & 63, wave = tid >> 6;
    int b = blockIdx.x, n0 = b << 7;
    for (int i = tid; i < 128 * 64; i += 1024) {
        int row = i >> 6, q = i & 63;
        unsigned u = (n0 + row < Nn) ? h[(size_t)(n0 + row) * 64 + q] : 0u;
        acc2[row * 64 + q] = pk64(u);
    }
    __syncthreads();
    int lo = keybase[b * NCH];
    int hi = (b == NBUCK2 - 1) ? *tot : keybase[(b + 1) * NCH];
    for (int base = lo + wave * 64; base < hi; base += 1024) {
        int idx = base + lane;
        unsigned pv = pairs[(idx < hi) ? idx : (hi - 1)];
        int m = hi - base; if (m > 64) m = 64;
        int j = 0;
        for (; j + 4 <= m; j += 4) {
            // scalar (SGPR) pair values -> SALU addressing, SGPR-base gathers
            unsigned p0 = sgpr((unsigned)__shfl((int)pv, j));
            unsigned p1 = sgpr((unsigned)__shfl((int)pv, j + 1));
            unsigned p2 = sgpr((unsigned)__shfl((int)pv, j + 2));
            unsigned p3 = sgpr((unsigned)__shfl((int)pv, j + 3));
            const unsigned* r0 = h + ((size_t)(p0 & 0x1FFFFu) << 6);
            const unsigned* r1 = h + ((size_t)(p1 & 0x1FFFFu) << 6);
            const unsigned* r2 = h + ((size_t)(p2 & 0x1FFFFu) << 6);
            const unsigned* r3 = h + ((size_t)(p3 & 0x1FFFFu) << 6);
            unsigned u0 = r0[lane];
            unsigned u1 = r1[lane];
            unsigned u2 = r2[lane];
            unsigned u3 = r3[lane];
            atomicAdd(&acc2[((p0 >> 17) << 6) + lane], pk64(u0));
            atomicAdd(&acc2[((p1 >> 17) << 6) + lane], pk64(u1));
            atomicAdd(&acc2[((p2 >> 17) << 6) + lane], pk64(u2));
            atomicAdd(&acc2[((p3 >> 17) << 6) + lane], pk64(u3));
        }
        for (; j < m; ++j) {
            unsigned p = sgpr((unsigned)__shfl((int)pv, j));
            unsigned u = (h + ((size_t)(p & 0x1FFFFu) << 6))[lane];
            atomicAdd(&acc2[((p >> 17) << 6) + lane], pk64(u));
        }
    }
    __syncthreads();
    int nn = Nn - n0; if (nn > 128) nn = 128;
    // out word q of hr = packbf(feat 2q, feat 2q+1); feat f<64 = lo(acc2[f]),
    // f>=64 = hi(acc2[f-64]); debias by nadds*32768 per field
    for (int i = tid; i < nn * 64; i += 1024) {
        int row = i >> 6, q = i & 63;
        float di = dinv[n0 + row];
        int nadds = cnt[n0 + row] + 1;
        float deb = (float)nadds * 32768.0f;
        int f0 = 2 * q, f1 = 2 * q + 1;
        unsigned long long v0 = acc2[row * 64 + (f0 & 63)];
        unsigned long long v1 = acc2[row * 64 + (f1 & 63)];
        float s0 = ((float)(unsigned)((f0 < 64) ? (v0 & 0xffffffffu) : (v0 >> 32)) - deb) * IQS;
        float s1 = ((float)(unsigned)((f1 < 64) ? (v1 & 0xffffffffu) : (v1 >> 32)) - deb) * IQS;
        float r0 = fmaxf(fmaf(di, s0, bias[f0]), 0.f);
        float r1 = fmaxf(fmaf(di, s1, bias[f1]), 0.f);
        out[(size_t)(n0 + row) * 64 + q] = packbf(r0, r1);
    }
}

// ---------- agg2: bucket(128 dst), u64 accum at [row*32+fl], 2 edges/step ----------
__global__ __launch_bounds__(1024) void agg2_k(const unsigned* __restrict__ h,
                                               const unsigned* __restrict__ pairs,
                                               const int* __restrict__ keybase,
                                               const int* __restrict__ tot,
                                               const int* __restrict__ cnt,
                                               const float* __restrict__ dinv,
                                               const float* __restrict__ bias,
                                               float* __restrict__ out, int Nn) {
    __shared__ unsigned long long acc2[128 * 32];  // [128][32] u64, word w = feats (w, w+32)
    int tid = threadIdx.x, lane = tid & 63, wave = tid >> 6;
    int half = lane >> 5, fl = lane & 31;
    int b = blockIdx.x, n0 = b << 7;
    for (int i = tid; i < 128 * 32; i += 1024) {
        int row = i >> 5, q = i & 31;
        unsigned u = (n0 + row < Nn) ? h[(size_t)(n0 + row) * 32 + q] : 0u;
        acc2[row * 32 + q] = pk64(u);
    }
    __syncthreads();
    int lo = keybase[b * NCH];
    int hi = (b == NBUCK2 - 1) ? *tot : keybase[(b + 1) * NCH];
    for (int base = lo + wave * 64; base < hi; base += 1024) {
        int idx = base + lane;
        unsigned pv = pairs[(idx < hi) ? idx : (hi - 1)];
        int m = hi - base; if (m > 64) m = 64;
        int j = 0;
        for (; j + 8 <= m; j += 8) {
            unsigned p0 = __shfl(pv, j + half);
            unsigned p1 = __shfl(pv, j + 2 + half);
            unsigned p2 = __shfl(pv, j + 4 + half);
            unsigned p3 = __shfl(pv, j + 6 + half);
            unsigned u0 = h[((p0 & 0x1FFFFu) << 5) + fl];
            unsigned u1 = h[((p1 & 0x1FFFFu) << 5) + fl];
            unsigned u2 = h[((p2 & 0x1FFFFu) << 5) + fl];
            unsigned u3 = h[((p3 & 0x1FFFFu) << 5) + fl];
            atomicAdd(&acc2[((p0 >> 17) << 5) + fl], pk64(u0));
            atomicAdd(&acc2[((p1 >> 17) << 5) + fl], pk64(u1));
            atomicAdd(&acc2[((p2 >> 17) << 5) + fl], pk64(u2));
            atomicAdd(&acc2[((p3 >> 17) << 5) + fl], pk64(u3));
        }
        for (; j < m; j += 2) {
            int q = j + half;
            unsigned p = __shfl(pv, (q < m) ? q : j);
            if (q < m) {
                unsigned u = h[((p & 0x1FFFFu) << 5) + fl];
                atomicAdd(&acc2[((p >> 17) << 5) + fl], pk64(u));
            }
        }
    }
    __syncthreads();
    int nn = Nn - n0; if (nn > 128) nn = 128;
    // out feat f<32 = lo(acc2[f]), f>=32 = hi(acc2[f-32]); debias
    for (int i = tid; i < nn * 64; i += 1024) {
        int row = i >> 6, f = i & 63;
        float di = dinv[n0 + row];
        int nadds = cnt[n0 + row] + 1;
        float deb = (float)nadds * 32768.0f;
        unsigned long long v = acc2[row * 32 + (f & 31)];
        float s = ((float)(unsigned)((f < 32) ? (v & 0xffffffffu) : (v >> 32)) - deb) * IQS;
        out[(size_t)(n0 + row) * 64 + f] = fmaf(di, s, bias[f]);
    }
}

// ---------- launch ----------
extern "C" void kernel_launch(void* const* d_in, const int* in_sizes, int n_in,
                              void* d_out, int out_size, void* d_ws, size_t ws_size,
                              hipStream_t stream) {
    const float* x  = (const float*)d_in[0];
    const void*  ei = d_in[1];
    const float* W1 = (const float*)d_in[2];
    const float* b1 = (const float*)d_in[3];
    const float* W2 = (const float*)d_in[4];
    const float* b2 = (const float*)d_in[5];

    const int N = N_NODES;
    const int E = in_sizes[1] / 2;

    char* w = (char*)d_ws;
    size_t off = 0;
    auto take = [&](size_t bytes) {
        void* p = w + off;
        off = (off + bytes + 255) & ~(size_t)255;
        return p;
    };
    int*   flag    = (int*)take(2 * sizeof(int));
    int*   tot     = flag + 1;
    int*   cnt     = (int*)take((size_t)N * 4);
    int*   bsumB   = (int*)take(4096 * 4);
    int*   colsum  = (int*)take((size_t)NKEY * 4);
    int*   keybase = (int*)take((size_t)NKEY * 4);
    float* dinv    = (float*)take((size_t)N * 4);
    unsigned* pairs = (unsigned*)take((size_t)E * 4);
    unsigned short* w1bf = (unsigned short*)take(128 * 128 * 2);
    unsigned short* w2bf = (unsigned short*)take(64 * 128 * 2);
    unsigned* hr   = (unsigned*)take((size_t)N * 64 * 4);   // bf16 [N][128] normal order
    unsigned* h2   = (unsigned*)take((size_t)N * 32 * 4);   // biased-u16 [N][64] interleaved
    (void)ws_size; (void)n_in; (void)out_size;

    // Staging tables ALIAS onto hr/h2 (both dead until after staging):
    //   bhist last read by colprefix_k; hr first written by agg1_k (later).
    //   bbase last read by write1_k;   h2 first written by gemm2_k (later).
    int* bhist = (int*)hr;
    int* bbase = (int*)h2;

    unsigned* h1 = (unsigned*)d_out;  // biased-u16 [N][128] interleaved, dead before agg2 writes

    const int nscanK = (NKEY + 1023) / 1024;   // 10
    const int ngridK = (NKEY + 255) / 256;     // 40

    detect64_k<<<1, 64, 0, stream>>>((const unsigned long long*)ei, flag);
    count1_k<<<NBLK2, 256, 0, stream>>>(ei, flag, bhist, E);
    colsum_k<<<ngridK, 256, 0, stream>>>(bhist, colsum);
    scan1_k<<<nscanK, 256, 0, stream>>>(colsum, keybase, bsumB, NKEY);
    scan2_k<<<1, 256, 0, stream>>>(bsumB, nscanK);
    scanadd_k<<<nscanK, 256, 0, stream>>>(bsumB, keybase, colsum, tot, NKEY);
    colprefix_k<<<ngridK, 256, 0, stream>>>(bhist, keybase, bbase);
    write1_k<<<NBLK2, 256, 0, stream>>>(ei, flag, bbase, pairs, E);
    degree_k<<<NBUCK2, 256, 0, stream>>>(pairs, keybase, tot, cnt, N);
    dinv_k<<<(N + 255) / 256, 256, 0, stream>>>(cnt, dinv, N);
    prep_w_k<<<64, 256, 0, stream>>>(W1, W2, w1bf, w2bf);

    gemm1_k<<<(N + 63) / 64, 256, 0, stream>>>(x, w1bf, dinv, h1, N);
    agg1_k<<<NBUCK2, 1024, 128 * 64 * 8, stream>>>(h1, pairs, keybase, tot, cnt, dinv, b1, hr, N);
    gemm2_k<<<(N + 63) / 64, 256, 0, stream>>>(hr, w2bf, dinv, h2, N);
    agg2_k<<<NBUCK2, 1024, 0, stream>>>(h2, pairs, keybase, tot, cnt, dinv, b2, (float*)d_out, N);
}

// Round 10
// 395.500 us; speedup vs baseline: 1.1745x; 1.1049x over previous
//
#include <hip/hip_runtime.h>

// 2-layer GCN, R22: revert to R14 (best measured, 394.7us) + 8-deep agg1 MLP.
// R15-R21 (chunked LDS-accumulator family) bottomed at 437us: the design is
// latency-bound on its bpermute->load->ds_add chain and carries a structural
// ~1.3x bucket-granularity tail (51.2MB accumulator footprint / 41MB LDS),
// plus costlier NKEY=10166 staging. R14's register-accumulation path has no
// atomics, no tail, cheap staging, and its agg1 (105us, VALUBusy 41%) is
// partially latency-exposed with only 4 gathers in flight.
// R22 = R14 verbatim, except agg1's inner loop issues 8 uint4 gathers
// (32 edges) per pass -- typical deg~32 row is one burst; VGPR ~60 keeps
// 8 waves/SIMD. Falsifier: agg1 >= 102us => random-gather L2-miss wall =>
// roofline.

#define N_NODES 100000
#define NBLK  512   // partition blocks
#define NBUCK 391   // ceil(100000/256) buckets of 256 dst nodes

typedef __attribute__((ext_vector_type(8))) short short8;
typedef __attribute__((ext_vector_type(4))) float f32x4;
typedef __attribute__((ext_vector_type(2))) float f32x2;

// ---------- bf16 helpers (RN-even) ----------
__device__ __forceinline__ unsigned short f2bf(float f) {
    union { float f; unsigned u; } c; c.f = f;
    unsigned r = (c.u + 0x7fffu + ((c.u >> 16) & 1u)) >> 16;
    return (unsigned short)r;
}
__device__ __forceinline__ float2 bfpair(unsigned u) {
    union { float f; unsigned u; } a, b;
    a.u = u << 16; b.u = u & 0xffff0000u;
    return make_float2(a.f, b.f);
}
__device__ __forceinline__ unsigned packbf(float a, float b) {
    return (unsigned)f2bf(a) | ((unsigned)f2bf(b) << 16);
}
// accumulate one packed-bf16 u32 into a packed f32x2 (lo feature, hi feature)
__device__ __forceinline__ void bfacc(unsigned u, f32x2& a) {
    union { unsigned u; float f; } lo, hi;
    lo.u = u << 16; hi.u = u & 0xffff0000u;
    f32x2 v = {lo.f, hi.f};
    a += v;   // v_pk_add_f32
}
__device__ __forceinline__ void bfacc4(uint4 u, f32x2& a0, f32x2& a1, f32x2& a2, f32x2& a3) {
    bfacc(u.x, a0); bfacc(u.y, a1); bfacc(u.z, a2); bfacc(u.w, a3);
}

// ---------- edge dtype detection (one wave) ----------
__global__ void detect64_k(const unsigned long long* __restrict__ ei, int* __restrict__ flag) {
    unsigned long long v = ei[threadIdx.x & 63];
    unsigned long long bad = __ballot(v >= (1ULL << 32));
    if (threadIdx.x == 0) *flag = (bad == 0ULL) ? 1 : 0;
}

__device__ __forceinline__ int edge_at(const void* ei, int is64, long long idx) {
    if (is64) return (int)((const long long*)ei)[idx];
    return ((const int*)ei)[idx];
}

// ---------- pass 1: per-block 391-bucket LDS histogram (NO global atomics) ----------
__global__ __launch_bounds__(256) void count1_k(const void* __restrict__ ei,
                                                const int* __restrict__ flag,
                                                int* __restrict__ bhist, int E) {
    __shared__ int lh[NBUCK];
    int t = threadIdx.x;
    for (int i = t; i < NBUCK; i += 256) lh[i] = 0;
    __syncthreads();
    int is64 = *flag;
    int C = (E + NBLK - 1) / NBLK;
    int lo = blockIdx.x * C;
    int hi = lo + C; if (hi > E) hi = E;
    for (int e = lo + t; e < hi; e += 256) {
        int d = edge_at(ei, is64, (long long)E + e);
        if ((unsigned)d < (unsigned)N_NODES) atomicAdd(&lh[d >> 8], 1);
    }
    __syncthreads();
    for (int i = t; i < NBUCK; i += 256) bhist[(size_t)i * NBLK + blockIdx.x] = lh[i];
}

// ---------- generic exclusive scan, 1024 elems/block ----------
__global__ void scan1_k(const int* __restrict__ cnt, int* __restrict__ partial,
                        int* __restrict__ bsum, int n) {
    __shared__ int sm[256];
    int t = threadIdx.x;
    int base = blockIdx.x * 1024 + t * 4;
    int v[4]; int loc = 0;
#pragma unroll
    for (int j = 0; j < 4; ++j) { v[j] = (base + j < n) ? cnt[base + j] : 0; loc += v[j]; }
    sm[t] = loc; __syncthreads();
    for (int off = 1; off < 256; off <<= 1) {
        int x = (t >= off) ? sm[t - off] : 0;
        __syncthreads();
        sm[t] += x;
        __syncthreads();
    }
    int incl = sm[t];
    int run = incl - loc;
    if (t == 255) bsum[blockIdx.x] = incl;
#pragma unroll
    for (int j = 0; j < 4; ++j) {
        if (base + j < n) partial[base + j] = run;
        run += v[j];
    }
}

__global__ void scan2_k(int* __restrict__ bsum, int nb) {
    __shared__ int sm[256];
    int t = threadIdx.x;
    int v = (t < nb) ? bsum[t] : 0;
    sm[t] = v; __syncthreads();
    for (int off = 1; off < 256; off <<= 1) {
        int x = (t >= off) ? sm[t - off] : 0;
        __syncthreads();
        sm[t] += x;
        __syncthreads();
    }
    if (t < nb) bsum[t] = sm[t] - v;
}

// finalize bucket-base scan in place; also emit total valid count
__global__ void scanadd_k(const int* __restrict__ bsum, int* __restrict__ arr,
                          const int* __restrict__ raw, int* __restrict__ tot, int n) {
    int base = blockIdx.x * 1024 + threadIdx.x * 4;
    int add = bsum[blockIdx.x];
#pragma unroll
    for (int j = 0; j < 4; ++j) {
        int i = base + j;
        if (i < n) {
            int v = arr[i] + add;
            arr[i] = v;
            if (i == n - 1) *tot = v + raw[i];
        }
    }
}

// finalize degree scan: row_ptr + dinv
__global__ void scan3_k(const int* __restrict__ bsum, const int* __restrict__ cnt,
                        int* __restrict__ row_ptr, float* __restrict__ dinv, int n) {
    int base = blockIdx.x * 1024 + threadIdx.x * 4;
    int add = bsum[blockIdx.x];
#pragma unroll
    for (int j = 0; j < 4; ++j) {
        int i = base + j;
        if (i < n) {
            row_ptr[i] += add;
            dinv[i] = rsqrtf((float)(cnt[i] + 1));  // +1 self-loop
        }
    }
}

// ---------- pass 2: deterministic staging write (src | dlocal<<17) ----------
__global__ __launch_bounds__(256) void write1_k(const void* __restrict__ ei,
                                                const int* __restrict__ flag,
                                                const int* __restrict__ bbase,
                                                unsigned* __restrict__ pairs, int E) {
    __shared__ int lofs[NBUCK];
    int t = threadIdx.x;
    for (int i = t; i < NBUCK; i += 256) lofs[i] = bbase[(size_t)i * NBLK + blockIdx.x];
    __syncthreads();
    int is64 = *flag;
    int C = (E + NBLK - 1) / NBLK;
    int lo = blockIdx.x * C;
    int hi = lo + C; if (hi > E) hi = E;
    for (int e = lo + t; e < hi; e += 256) {
        int s = edge_at(ei, is64, e);
        int d = edge_at(ei, is64, (long long)E + e);
        if ((unsigned)d >= (unsigned)N_NODES) continue;         // must match count1 filter
        if ((unsigned)s >= (unsigned)N_NODES) s = 0;            // clamp keeps counts consistent
        int b = d >> 8;
        int p = atomicAdd(&lofs[b], 1);  // LDS atomic; per-block fronts contiguous
        pairs[p] = (unsigned)s | ((unsigned)(d & 255) << 17);
    }
}

// ---------- degrees from staged pairs: one block per bucket, block-private writes ----------
__global__ __launch_bounds__(256) void degree_k(const unsigned* __restrict__ pairs,
                                                const int* __restrict__ bbase,
                                                const int* __restrict__ tot,
                                                int* __restrict__ cnt, int Nn) {
    __shared__ int lh[256];
    int b = blockIdx.x;
    int t = threadIdx.x;
    lh[t] = 0;
    __syncthreads();
    int lo = bbase[(size_t)b * NBLK];
    int hi = (b == NBUCK - 1) ? *tot : bbase[((size_t)b + 1) * NBLK];
    for (int i = lo + t; i < hi; i += 256) {
        unsigned p = __builtin_nontemporal_load(pairs + i);
        atomicAdd(&lh[p >> 17], 1);
    }
    __syncthreads();
    int n0 = b << 8;
    if (n0 + t < Nn) cnt[n0 + t] = lh[t];
}

// ---------- pass 3: block-private scatter into exact CSR positions ----------
__global__ __launch_bounds__(256) void fill3_k(const unsigned* __restrict__ pairs,
                                               const int* __restrict__ bbase,
                                               const int* __restrict__ tot,
                                               const int* __restrict__ row_ptr,
                                               int* __restrict__ colv, int Nn) {
    __shared__ int cur[256];
    int b = blockIdx.x;
    int t = threadIdx.x;
    int n0 = b << 8;
    int nn = Nn - n0; if (nn > 256) nn = 256;
    if (t < nn) cur[t] = row_ptr[n0 + t];
    __syncthreads();
    int lo = bbase[(size_t)b * NBLK];
    int hi = (b == NBUCK - 1) ? *tot : bbase[((size_t)b + 1) * NBLK];
    for (int i = lo + t; i < hi; i += 256) {
        unsigned p = __builtin_nontemporal_load(pairs + i);
        int dl = (int)(p >> 17);
        int slot = atomicAdd(&cur[dl], 1);
        colv[slot] = (int)(p & 0x1FFFFu);   // block-private ~32KB range: no line sharing
    }
}

// ---------- weight prep: W^T in bf16 ----------
__global__ void prep_w_k(const float* __restrict__ W1, const float* __restrict__ W2,
                         unsigned short* __restrict__ w1bf, unsigned short* __restrict__ w2bf) {
    int i = blockIdx.x * 256 + threadIdx.x;
    if (i < 128 * 128) { int k = i >> 7, f = i & 127; w1bf[f * 128 + k] = f2bf(W1[i]); }
    if (i < 128 * 64)  { int k = i >> 6, f = i & 63;  w2bf[f * 128 + k] = f2bf(W2[i]); }
}

// ---------- GEMM1 (MFMA): h1[n][128] bf16 node-major = dinv[n] * (x @ W1) ----------
__global__ __launch_bounds__(256) void gemm1_k(const float* __restrict__ x,
                                               const unsigned short* __restrict__ w1bf,
                                               const float* __restrict__ dinv,
                                               unsigned* __restrict__ h1, int Nn) {
    __shared__ __align__(16) unsigned short sA[128][136];  // W1^T [feat][k]
    __shared__ __align__(16) unsigned short sB[64][136];   // x [node][k] bf16
    int tid = threadIdx.x;
    int n0g = blockIdx.x * 64;
    {
        const uint4* src = (const uint4*)w1bf;
#pragma unroll
        for (int l = 0; l < 8; ++l) {
            int idx = tid + l * 256;
            int f = idx >> 4, kq = idx & 15;
            *(uint4*)&sA[f][kq * 8] = src[idx];
        }
    }
    {
        int n = tid >> 2, kq = tid & 3;
        int gn = n0g + n; if (gn >= Nn) gn = Nn - 1;
        const float4* xr = (const float4*)(x + (size_t)gn * 128 + kq * 32);
        unsigned short* dst = &sB[n][kq * 32];
#pragma unroll
        for (int i = 0; i < 8; ++i) {
            float4 v = xr[i];
            dst[i * 4 + 0] = f2bf(v.x); dst[i * 4 + 1] = f2bf(v.y);
            dst[i * 4 + 2] = f2bf(v.z); dst[i * 4 + 3] = f2bf(v.w);
        }
    }
    __syncthreads();
    int wave = tid >> 6, lane = tid & 63;
    int quad = lane >> 4, l16 = lane & 15;
    f32x4 z = {0.f, 0.f, 0.f, 0.f};
    f32x4 acc[8];
#pragma unroll
    for (int t = 0; t < 8; ++t) acc[t] = z;
#pragma unroll
    for (int kk = 0; kk < 4; ++kk) {
        int kb = kk * 32 + quad * 8;
        short8 a = *(const short8*)&sB[wave * 16 + l16][kb];
#pragma unroll
        for (int ft = 0; ft < 8; ++ft) {
            short8 b = *(const short8*)&sA[ft * 16 + l16][kb];
            acc[ft] = __builtin_amdgcn_mfma_f32_16x16x32_bf16(a, b, acc[ft], 0, 0, 0);
        }
    }
    // per-row dinv for pre-scaled h' = dinv * h
    float dv[4];
#pragma unroll
    for (int r = 0; r < 4; ++r) {
        int gn = n0g + wave * 16 + quad * 4 + r;
        if (gn >= Nn) gn = Nn - 1;
        dv[r] = dinv[gn];
    }
    __syncthreads();  // reuse sA as transpose buffer
    unsigned short (*sC)[136] = sA;
#pragma unroll
    for (int ft = 0; ft < 8; ++ft)
#pragma unroll
        for (int r = 0; r < 4; ++r)
            sC[wave * 16 + quad * 4 + r][ft * 16 + l16] = f2bf(dv[r] * acc[ft][r]);
    __syncthreads();
#pragma unroll
    for (int l = 0; l < 4; ++l) {
        int idx = tid + l * 256;
        int row = idx >> 4, q = idx & 15;
        int gn = n0g + row;
        if (gn < Nn)
            *(uint4*)&h1[(size_t)gn * 64 + q * 4] = *(uint4*)&sC[row][q * 8];
    }
}

// ---------- GEMM2 (MFMA): h2[n][64] bf16 node-major = dinv[n] * (hr @ W2) ----------
__global__ __launch_bounds__(256) void gemm2_k(const unsigned* __restrict__ hr,
                                               const unsigned short* __restrict__ w2bf,
                                               const float* __restrict__ dinv,
                                               unsigned* __restrict__ h2, int Nn) {
    __shared__ __align__(16) unsigned short sA[64][136];
    __shared__ __align__(16) unsigned short sB[64][136];
    int tid = threadIdx.x;
    int n0g = blockIdx.x * 64;
    {
        const uint4* src = (const uint4*)w2bf;
#pragma unroll
        for (int l = 0; l < 4; ++l) {
            int idx = tid + l * 256;
            int f = idx >> 4, kq = idx & 15;
            *(uint4*)&sA[f][kq * 8] = src[idx];
        }
    }
    {
        const uint4* src = (const uint4*)hr;
#pragma unroll
        for (int l = 0; l < 4; ++l) {
            int idx = tid + l * 256;
            int row = idx >> 4, q = idx & 15;
            int gn = n0g + row; if (gn >= Nn) gn = Nn - 1;
            *(uint4*)&sB[row][q * 8] = src[(size_t)gn * 16 + q];
        }
    }
    __syncthreads();
    int wave = tid >> 6, lane = tid & 63;
    int quad = lane >> 4, l16 = lane & 15;
    f32x4 z = {0.f, 0.f, 0.f, 0.f};
    f32x4 acc[4];
#pragma unroll
    for (int t = 0; t < 4; ++t) acc[t] = z;
#pragma unroll
    for (int kk = 0; kk < 4; ++kk) {
        int kb = kk * 32 + quad * 8;
        short8 a = *(const short8*)&sB[wave * 16 + l16][kb];
#pragma unroll
        for (int ft = 0; ft < 4; ++ft) {
            short8 b = *(const short8*)&sA[ft * 16 + l16][kb];
            acc[ft] = __builtin_amdgcn_mfma_f32_16x16x32_bf16(a, b, acc[ft], 0, 0, 0);
        }
    }
    float dv[4];
#pragma unroll
    for (int r = 0; r < 4; ++r) {
        int gn = n0g + wave * 16 + quad * 4 + r;
        if (gn >= Nn) gn = Nn - 1;
        dv[r] = dinv[gn];
    }
    __syncthreads();
    unsigned short (*sC)[136] = sA;
#pragma unroll
    for (int ft = 0; ft < 4; ++ft)
#pragma unroll
        for (int r = 0; r < 4; ++r)
            sC[wave * 16 + quad * 4 + r][ft * 16 + l16] = f2bf(dv[r] * acc[ft][r]);
    __syncthreads();
#pragma unroll
    for (int l = 0; l < 2; ++l) {
        int idx = tid + l * 256;
        int row = idx >> 3, q = idx & 7;
        int gn = n0g + row;
        if (gn < Nn)
            *(uint4*)&h2[(size_t)gn * 32 + q * 4] = *(uint4*)&sC[row][q * 8];
    }
}

// ---------- agg1: wave=node, uint4 gathers (16 lanes/row), 8 loads in flight ----------
// h pre-scaled by dinv[src]; out[dst] = relu( di * (sum h'[src] + h'[self]) + b )
__global__ __launch_bounds__(256) void agg1_k(const unsigned* __restrict__ h,
                                              const int* __restrict__ row_ptr,
                                              const int* __restrict__ cnt,
                                              const int* __restrict__ colv,
                                              const float* __restrict__ dinv,
                                              const float* __restrict__ bias,
                                              unsigned* __restrict__ out, int Nn, int E) {
    int node = blockIdx.x * 4 + (threadIdx.x >> 6);
    if (node >= Nn) return;
    int lane = threadIdx.x & 63;
    int qtr = lane >> 4, fp = lane & 15;   // 16 lanes x 16B = one 256B row
    float di = dinv[node];
    int start = row_ptr[node];
    int deg = cnt[node];
    const uint4* hq = (const uint4*)h;     // row = 16 uint4

    f32x2 a0 = {0.f, 0.f}, a1 = a0, a2 = a0, a3 = a0;  // features 8fp..8fp+7
    if (qtr == 0) {
        uint4 u = hq[(size_t)node * 16 + fp];          // self (already * di)
        bfacc4(u, a0, a1, a2, a3);
    }

    for (int base = 0; base < deg; base += 64) {
        int idx = base + lane;
        int ci = start + idx; if (ci >= E) ci = E - 1;
        int sl = colv[ci];
        int m = deg - base; if (m > 64) m = 64;
        int j = 0;
        for (; j + 32 <= m; j += 32) {     // 8 loads x 4 edges in flight
            int s0 = __shfl(sl, j + qtr);
            int s1 = __shfl(sl, j + 4 + qtr);
            int s2 = __shfl(sl, j + 8 + qtr);
            int s3 = __shfl(sl, j + 12 + qtr);
            int s4 = __shfl(sl, j + 16 + qtr);
            int s5 = __shfl(sl, j + 20 + qtr);
            int s6 = __shfl(sl, j + 24 + qtr);
            int s7 = __shfl(sl, j + 28 + qtr);
            uint4 u0 = hq[(size_t)s0 * 16 + fp];
            uint4 u1 = hq[(size_t)s1 * 16 + fp];
            uint4 u2 = hq[(size_t)s2 * 16 + fp];
            uint4 u3 = hq[(size_t)s3 * 16 + fp];
            uint4 u4 = hq[(size_t)s4 * 16 + fp];
            uint4 u5 = hq[(size_t)s5 * 16 + fp];
            uint4 u6 = hq[(size_t)s6 * 16 + fp];
            uint4 u7 = hq[(size_t)s7 * 16 + fp];
            bfacc4(u0, a0, a1, a2, a3);
            bfacc4(u1, a0, a1, a2, a3);
            bfacc4(u2, a0, a1, a2, a3);
            bfacc4(u3, a0, a1, a2, a3);
            bfacc4(u4, a0, a1, a2, a3);
            bfacc4(u5, a0, a1, a2, a3);
            bfacc4(u6, a0, a1, a2, a3);
            bfacc4(u7, a0, a1, a2, a3);
        }
        for (; j + 16 <= m; j += 16) {     // 4 loads x 4 edges
            int s0 = __shfl(sl, j + qtr);
            int s1 = __shfl(sl, j + 4 + qtr);
            int s2 = __shfl(sl, j + 8 + qtr);
            int s3 = __shfl(sl, j + 12 + qtr);
            uint4 u0 = hq[(size_t)s0 * 16 + fp];
            uint4 u1 = hq[(size_t)s1 * 16 + fp];
            uint4 u2 = hq[(size_t)s2 * 16 + fp];
            uint4 u3 = hq[(size_t)s3 * 16 + fp];
            bfacc4(u0, a0, a1, a2, a3);
            bfacc4(u1, a0, a1, a2, a3);
            bfacc4(u2, a0, a1, a2, a3);
            bfacc4(u3, a0, a1, a2, a3);
        }
        for (; j + 4 <= m; j += 4) {
            int s0 = __shfl(sl, j + qtr);
            uint4 u0 = hq[(size_t)s0 * 16 + fp];
            bfacc4(u0, a0, a1, a2, a3);
        }
        if (j < m) {                        // 1..3 edges left
            int q = j + qtr;
            int s = __shfl(sl, (q < m) ? q : j);
            if (q < m) {
                uint4 u = hq[(size_t)s * 16 + fp];
                bfacc4(u, a0, a1, a2, a3);
            }
        }
    }
    // combine the 4 quarter-copies of each feature
#define RED2(v) v += __shfl_xor(v, 32); v += __shfl_xor(v, 16)
    RED2(a0.x); RED2(a0.y); RED2(a1.x); RED2(a1.y);
    RED2(a2.x); RED2(a2.y); RED2(a3.x); RED2(a3.y);
#undef RED2
    if (qtr == 0) {
        float4 b0 = *(const float4*)&bias[8 * fp];
        float4 b1 = *(const float4*)&bias[8 * fp + 4];
        uint4 o;
        o.x = packbf(fmaxf(fmaf(di, a0.x, b0.x), 0.f), fmaxf(fmaf(di, a0.y, b0.y), 0.f));
        o.y = packbf(fmaxf(fmaf(di, a1.x, b0.z), 0.f), fmaxf(fmaf(di, a1.y, b0.w), 0.f));
        o.z = packbf(fmaxf(fmaf(di, a2.x, b1.x), 0.f), fmaxf(fmaf(di, a2.y, b1.y), 0.f));
        o.w = packbf(fmaxf(fmaf(di, a3.x, b1.z), 0.f), fmaxf(fmaf(di, a3.y, b1.w), 0.f));
        *(uint4*)&out[(size_t)node * 64 + 4 * fp] = o;   // regular store: gemm2 re-reads
    }
}

// ---------- agg2: wave=node, uint4 gathers (8 lanes/row, 8 edges/load) ----------
__global__ __launch_bounds__(256) void agg2_k(const unsigned* __restrict__ h,
                                              const int* __restrict__ row_ptr,
                                              const int* __restrict__ cnt,
                                              const int* __restrict__ colv,
                                              const float* __restrict__ dinv,
                                              const float* __restrict__ bias,
                                              float* __restrict__ out, int Nn, int E) {
    int node = blockIdx.x * 4 + (threadIdx.x >> 6);
    if (node >= Nn) return;
    int lane = threadIdx.x & 63;
    int oct = lane >> 3, fp = lane & 7;    // 8 lanes x 16B = one 128B row
    float di = dinv[node];
    int start = row_ptr[node];
    int deg = cnt[node];
    const uint4* hq = (const uint4*)h;     // row = 8 uint4

    f32x2 a0 = {0.f, 0.f}, a1 = a0, a2 = a0, a3 = a0;  // features 8fp..8fp+7
    if (oct == 0) {
        uint4 u = hq[(size_t)node * 8 + fp];           // self (already * di)
        bfacc4(u, a0, a1, a2, a3);
    }

    for (int base = 0; base < deg; base += 64) {
        int idx = base + lane;
        int ci = start + idx; if (ci >= E) ci = E - 1;
        int sl = __builtin_nontemporal_load(colv + ci);
        int m = deg - base; if (m > 64) m = 64;
        int j = 0;
        for (; j + 32 <= m; j += 32) {     // 4 loads x 8 edges
            int s0 = __shfl(sl, j + oct);
            int s1 = __shfl(sl, j + 8 + oct);
            int s2 = __shfl(sl, j + 16 + oct);
            int s3 = __shfl(sl, j + 24 + oct);
            uint4 u0 = hq[(size_t)s0 * 8 + fp];
            uint4 u1 = hq[(size_t)s1 * 8 + fp];
            uint4 u2 = hq[(size_t)s2 * 8 + fp];
            uint4 u3 = hq[(size_t)s3 * 8 + fp];
            bfacc4(u0, a0, a1, a2, a3);
            bfacc4(u1, a0, a1, a2, a3);
            bfacc4(u2, a0, a1, a2, a3);
            bfacc4(u3, a0, a1, a2, a3);
        }
        for (; j + 8 <= m; j += 8) {
            int s0 = __shfl(sl, j + oct);
            uint4 u0 = hq[(size_t)s0 * 8 + fp];
            bfacc4(u0, a0, a1, a2, a3);
        }
        if (j < m) {                        // 1..7 edges left
            int q = j + oct;
            int s = __shfl(sl, (q < m) ? q : j);
            if (q < m) {
                uint4 u = hq[(size_t)s * 8 + fp];
                bfacc4(u, a0, a1, a2, a3);
            }
        }
    }
    // combine the 8 octet-copies of each feature
#define RED3(v) v += __shfl_xor(v, 32); v += __shfl_xor(v, 16); v += __shfl_xor(v, 8)
    RED3(a0.x); RED3(a0.y); RED3(a1.x); RED3(a1.y);
    RED3(a2.x); RED3(a2.y); RED3(a3.x); RED3(a3.y);
#undef RED3
    if (oct == 0) {
        float4 b0 = *(const float4*)&bias[8 * fp];
        float4 b1 = *(const float4*)&bias[8 * fp + 4];
        float4 o0 = make_float4(fmaf(di, a0.x, b0.x), fmaf(di, a0.y, b0.y),
                                fmaf(di, a1.x, b0.z), fmaf(di, a1.y, b0.w));
        float4 o1 = make_float4(fmaf(di, a2.x, b1.x), fmaf(di, a2.y, b1.y),
                                fmaf(di, a3.x, b1.z), fmaf(di, a3.y, b1.w));
        *(float4*)&out[(size_t)node * 64 + 8 * fp]     = o0;
        *(float4*)&out[(size_t)node * 64 + 8 * fp + 4] = o1;
    }
}

// ---------- launch ----------
extern "C" void kernel_launch(void* const* d_in, const int* in_sizes, int n_in,
                              void* d_out, int out_size, void* d_ws, size_t ws_size,
                              hipStream_t stream) {
    const float* x  = (const float*)d_in[0];
    const void*  ei = d_in[1];
    const float* W1 = (const float*)d_in[2];
    const float* b1 = (const float*)d_in[3];
    const float* W2 = (const float*)d_in[4];
    const float* b2 = (const float*)d_in[5];

    const int N = N_NODES;
    const int E = in_sizes[1] / 2;
    const int NB = NBLK * NBUCK;  // 200192

    char* w = (char*)d_ws;
    size_t off = 0;
    auto take = [&](size_t bytes) {
        void* p = w + off;
        off = (off + bytes + 255) & ~(size_t)255;
        return p;
    };
    int*   flag    = (int*)take(2 * sizeof(int));
    int*   tot     = flag + 1;
    int*   cnt     = (int*)take((size_t)N * 4);
    int*   row_ptr = (int*)take((size_t)N * 4);
    int*   bsumA   = (int*)take(256 * 4);
    int*   bsumB   = (int*)take(256 * 4);
    int*   bhist   = (int*)take((size_t)NB * 4);
    int*   bbase   = (int*)take((size_t)NB * 4);
    float* dinv    = (float*)take((size_t)N * 4);
    unsigned* pairs = (unsigned*)take((size_t)E * 4);
    int*   colv    = (int*)take((size_t)E * 4);
    unsigned short* w1bf = (unsigned short*)take(128 * 128 * 2);
    unsigned short* w2bf = (unsigned short*)take(64 * 128 * 2);
    unsigned* hr   = (unsigned*)take((size_t)N * 64 * 4);   // bf16 [N][128]
    unsigned* h2   = (unsigned*)take((size_t)N * 32 * 4);   // bf16 [N][64]
    (void)ws_size; (void)n_in; (void)out_size;

    unsigned* h1 = (unsigned*)d_out;  // bf16 [N][128] in d_out, dead before agg2 writes

    const int nscanN = (N + 1023) / 1024;   // 98
    const int nscanB = (NB + 1023) / 1024;  // 196

    detect64_k<<<1, 64, 0, stream>>>((const unsigned long long*)ei, flag);
    count1_k<<<NBLK, 256, 0, stream>>>(ei, flag, bhist, E);
    // bucket-base scan (exclusive over bucket-major [NBUCK][NBLK])
    scan1_k<<<nscanB, 256, 0, stream>>>(bhist, bbase, bsumB, NB);
    scan2_k<<<1, 256, 0, stream>>>(bsumB, nscanB);
    scanadd_k<<<nscanB, 256, 0, stream>>>(bsumB, bbase, bhist, tot, NB);
    // stage pairs, then block-private degrees
    write1_k<<<NBLK, 256, 0, stream>>>(ei, flag, bbase, pairs, E);
    degree_k<<<NBUCK, 256, 0, stream>>>(pairs, bbase, tot, cnt, N);
    // degree scan -> row_ptr, dinv
    scan1_k<<<nscanN, 256, 0, stream>>>(cnt, row_ptr, bsumA, N);
    scan2_k<<<1, 256, 0, stream>>>(bsumA, nscanN);
    scan3_k<<<nscanN, 256, 0, stream>>>(bsumA, cnt, row_ptr, dinv, N);
    // block-private CSR scatter
    fill3_k<<<NBUCK, 256, 0, stream>>>(pairs, bbase, tot, row_ptr, colv, N);
    prep_w_k<<<64, 256, 0, stream>>>(W1, W2, w1bf, w2bf);

    gemm1_k<<<(N + 63) / 64, 256, 0, stream>>>(x, w1bf, dinv, h1, N);
    agg1_k<<<(N + 3) / 4, 256, 0, stream>>>(h1, row_ptr, cnt, colv, dinv, b1, hr, N, E);
    gemm2_k<<<(N + 63) / 64, 256, 0, stream>>>(hr, w2bf, dinv, h2, N);
    agg2_k<<<(N + 3) / 4, 256, 0, stream>>>(h2, row_ptr, cnt, colv, dinv, b2, (float*)d_out, N, E);
}